// Round 1
// baseline (373.926 us; speedup 1.0000x reference)
//
#include <hip/hip_runtime.h>

#define NINST 100
#define MLOG 28
#define IMG 800
#define LOGSZ (MLOG * MLOG) /* 784 */

// ws layout (in 32-bit words):
//  [0..99]    order (original index of n-th highest cls_prob)
//  [100..199] cls (0-based class of ordered instance)
//  [200..599] box (x0,y0,x1,y1 per ordered instance, int-truncated)
//  [600..699] msum (mask pixel count per ordered instance)
//  [800..899] slot_n (ordered-instance index for output slot s)
//  [900]      nkeep
//  [1024..]   bit-packed masks, per-instance stride 3648 words (12 words x 304 rows),
//             word columns aligned to the GLOBAL word grid (word = x/32) so
//             cross-instance intersection is a plain AND.
#define OFF_ORDER 0
#define OFF_CLS   100
#define OFF_BOX   200
#define OFF_MSUM  600
#define OFF_SLOT  800
#define OFF_NK    900
#define OFF_MASK  1024
#define ROWW      12
#define MSTRIDE   (ROWW * 304)

__global__ __launch_bounds__(128) void k_rank(const float* __restrict__ cls_prob,
                                              const float* __restrict__ rois,
                                              const int* __restrict__ cls_idx,
                                              int* __restrict__ ws) {
    __shared__ int s_order[NINST];
    int t = threadIdx.x;
    if (t < NINST) {
        float p = cls_prob[t];
        int r = 0;
        for (int j = 0; j < NINST; j++) {
            float q = cls_prob[j];
            r += (q > p) || (q == p && j < t); // stable argsort(-cls_prob)
        }
        s_order[r] = t;
    }
    __syncthreads();
    if (t < NINST) {
        int o = s_order[t];
        ws[OFF_ORDER + t] = o;
        ws[OFF_CLS + t] = cls_idx[o] - 1;
#pragma unroll
        for (int k = 0; k < 4; k++)
            ws[OFF_BOX + 4 * t + k] = (int)rois[4 * o + k]; // trunc-toward-zero == astype(int32)
    }
}

// One block per ordered instance: rasterize mask bits + count msum.
__global__ __launch_bounds__(256) void k_mask(const float* __restrict__ mask_prob,
                                              int* __restrict__ ws) {
    int n = blockIdx.x, tid = threadIdx.x;
    __shared__ float lg[LOGSZ];
    __shared__ int red[256];
    const int* box = ws + OFF_BOX;
    int x0 = box[4 * n], y0 = box[4 * n + 1], x1 = box[4 * n + 2], y1 = box[4 * n + 3];
    int xs = max(x0, 0), xe = min(x1 + 1, IMG);
    int ys = max(y0, 0), ye = min(y1 + 1, IMG);
    int wx0 = xs >> 5, nw = ((xe + 31) >> 5) - wx0, nrows = ye - ys;
    int orig = ws[OFF_ORDER + n];
    for (int i = tid; i < LOGSZ; i += 256) lg[i] = mask_prob[orig * LOGSZ + i];
    __syncthreads();
    float wf = fmaxf((float)(x1 - x0 + 1), 1.f), hf = fmaxf((float)(y1 - y0 + 1), 1.f);
    float rx = 28.f / wf, ry = 28.f / hf;
    unsigned* mb = (unsigned*)(ws + OFF_MASK) + n * MSTRIDE;
    int total = nrows * nw, cnt = 0;
    for (int t = tid; t < total; t += 256) {
        int row = t / nw, wc = t - row * nw;
        int y = ys + row;
        float sy = ((float)y - (float)y0 + 0.5f) * ry - 0.5f;
        sy = fminf(fmaxf(sy, 0.f), 27.f);
        int iy0 = (int)sy, iy1 = min(iy0 + 1, 27);
        float fy = sy - (float)iy0;
        const float* r0 = lg + iy0 * MLOG;
        const float* r1 = lg + iy1 * MLOG;
        unsigned bits = 0u;
        int xbase = (wx0 + wc) << 5;
        int j0 = max(xs - xbase, 0), j1 = min(xe - xbase, 32);
        for (int j = j0; j < j1; j++) {
            int xx = xbase + j;
            float sx = ((float)xx - (float)x0 + 0.5f) * rx - 0.5f;
            sx = fminf(fmaxf(sx, 0.f), 27.f);
            int ix0 = (int)sx, ix1 = min(ix0 + 1, 27);
            float fx = sx - (float)ix0;
            float val = (1.f - fy) * ((1.f - fx) * r0[ix0] + fx * r0[ix1]) +
                        fy * ((1.f - fx) * r1[ix0] + fx * r1[ix1]);
            bits |= (val > 0.f) ? (1u << j) : 0u;
        }
        mb[row * ROWW + wc] = bits;
        cnt += __popc(bits);
    }
    red[tid] = cnt;
    __syncthreads();
    for (int s = 128; s; s >>= 1) {
        if (tid < s) red[tid] += red[tid + s];
        __syncthreads();
    }
    if (tid == 0) ws[OFF_MSUM + n] = red[0];
}

// Single block: sequential keep scan. Overlap only couples same-class
// box-overlapping earlier KEPT instances; union computed on the fly.
__global__ __launch_bounds__(256) void k_scan(int* __restrict__ ws, float* __restrict__ out) {
    int tid = threadIdx.x;
    __shared__ int s_box[4 * NINST];
    __shared__ int s_cls[NINST];
    __shared__ int s_msum[NINST];
    __shared__ int s_keep[NINST];
    __shared__ int s_cand[32];
    __shared__ int s_ncand;
    __shared__ int red[256];
    for (int i = tid; i < NINST; i += 256) {
        s_cls[i] = ws[OFF_CLS + i];
        s_msum[i] = ws[OFF_MSUM + i];
    }
    for (int i = tid; i < 4 * NINST; i += 256) s_box[i] = ws[OFF_BOX + i];
    const unsigned* maskbase = (const unsigned*)(ws + OFF_MASK);
    __syncthreads();

    for (int n = 0; n < NINST; n++) {
        if (tid == 0) s_ncand = 0;
        __syncthreads(); // also publishes s_keep[n-1]
        if (tid < n && s_cls[tid] == s_cls[n] && s_keep[tid]) {
            int axs = max(s_box[4 * tid], 0), axe = min(s_box[4 * tid + 2] + 1, IMG);
            int ays = max(s_box[4 * tid + 1], 0), aye = min(s_box[4 * tid + 3] + 1, IMG);
            int nxs = max(s_box[4 * n], 0), nxe = min(s_box[4 * n + 2] + 1, IMG);
            int nys = max(s_box[4 * n + 1], 0), nye = min(s_box[4 * n + 3] + 1, IMG);
            if (axs < nxe && nxs < axe && ays < nye && nys < aye) {
                int k = atomicAdd(&s_ncand, 1);
                if (k < 32) s_cand[k] = tid;
            }
        }
        __syncthreads();
        int nc = min(s_ncand, 32);
        if (nc == 0) { // ovl==0 -> keep iff msum>0; skip reduction entirely
            if (tid == 0) s_keep[n] = (s_msum[n] > 0);
            continue;
        }
        int nxs = max(s_box[4 * n], 0), nxe = min(s_box[4 * n + 2] + 1, IMG);
        int nys = max(s_box[4 * n + 1], 0), nye = min(s_box[4 * n + 3] + 1, IMG);
        int wx0 = nxs >> 5, nw = ((nxe + 31) >> 5) - wx0, nrows = nye - nys;
        const unsigned* mn = maskbase + n * MSTRIDE;
        int total = nrows * nw, ovl = 0;
        for (int t = tid; t < total; t += 256) {
            int row = t / nw, wc = t - row * nw;
            unsigned bits = mn[row * ROWW + wc];
            if (!bits) continue;
            int y = nys + row, wa = wx0 + wc;
            unsigned img = 0;
            for (int k = 0; k < nc; k++) {
                int m = s_cand[k];
                int mys = max(s_box[4 * m + 1], 0), mye = min(s_box[4 * m + 3] + 1, IMG);
                int mxs = max(s_box[4 * m], 0), mxe = min(s_box[4 * m + 2] + 1, IMG);
                int mwx0 = mxs >> 5, mnw = ((mxe + 31) >> 5) - mwx0;
                int rr = y - mys, cc = wa - mwx0;
                if (rr >= 0 && rr < (mye - mys) && cc >= 0 && cc < mnw)
                    img |= maskbase[m * MSTRIDE + rr * ROWW + cc];
            }
            ovl += __popc(bits & img);
        }
        red[tid] = ovl;
        __syncthreads();
        for (int s = 128; s; s >>= 1) {
            if (tid < s) red[tid] += red[tid + s];
            __syncthreads();
        }
        if (tid == 0) {
            int msum = s_msum[n];
            s_keep[n] = (msum > 0) && ((float)red[0] <= 0.3f * (float)msum);
        }
    }
    __syncthreads();
    if (tid == 0) {
        int nk = 0;
        for (int n = 0; n < NINST; n++) {
            if (s_keep[n]) {
                ws[OFF_SLOT + nk] = n;
                out[nk] = (float)ws[OFF_ORDER + n]; // keep_inds as float
                nk++;
            }
        }
        ws[OFF_NK] = nk;
        for (int s = nk; s < NINST; s++) out[s] = -1.f;
    }
}

// Fused zero + energy write: every output element written exactly once.
__global__ __launch_bounds__(256) void k_out(const float* __restrict__ mask_prob,
                                             const int* __restrict__ ws,
                                             float* __restrict__ out) {
    int slot = blockIdx.y;
    int pi = blockIdx.x * 256 + threadIdx.x;
    int p = pi * 4;
    float4 res = make_float4(0.f, 0.f, 0.f, 0.f);
    int nk = ws[OFF_NK];
    if (slot < nk) {
        int n = ws[OFF_SLOT + slot];
        const int* box = ws + OFF_BOX;
        int x0 = box[4 * n], y0 = box[4 * n + 1], x1 = box[4 * n + 2], y1 = box[4 * n + 3];
        int xs = max(x0, 0), xe = min(x1 + 1, IMG);
        int ys = max(y0, 0), ye = min(y1 + 1, IMG);
        int y = p / IMG, x = p - y * IMG;
        if (y >= ys && y < ye && x + 3 >= xs && x < xe) {
            int orig = ws[OFF_ORDER + n];
            const float* lg = mask_prob + orig * LOGSZ;
            float wf = fmaxf((float)(x1 - x0 + 1), 1.f), hf = fmaxf((float)(y1 - y0 + 1), 1.f);
            float rx = 28.f / wf, ry = 28.f / hf;
            float sy = ((float)y - (float)y0 + 0.5f) * ry - 0.5f;
            sy = fminf(fmaxf(sy, 0.f), 27.f);
            int iy0 = (int)sy, iy1 = min(iy0 + 1, 27);
            float fy = sy - (float)iy0;
            const float* r0 = lg + iy0 * MLOG;
            const float* r1 = lg + iy1 * MLOG;
            float v[4];
#pragma unroll
            for (int j = 0; j < 4; j++) {
                int xx = x + j;
                float val = 0.f;
                if (xx >= xs && xx < xe) {
                    float sx = ((float)xx - (float)x0 + 0.5f) * rx - 0.5f;
                    sx = fminf(fmaxf(sx, 0.f), 27.f);
                    int ix0 = (int)sx, ix1 = min(ix0 + 1, 27);
                    float fx = sx - (float)ix0;
                    val = (1.f - fy) * ((1.f - fx) * r0[ix0] + fx * r0[ix1]) +
                          fy * ((1.f - fx) * r1[ix0] + fx * r1[ix1]);
                }
                v[j] = val;
            }
            res = make_float4(v[0], v[1], v[2], v[3]);
        }
    }
    float4* dst = ((float4*)(out + NINST)) + (size_t)slot * (IMG * IMG / 4) + pi;
    *dst = res;
}

extern "C" void kernel_launch(void* const* d_in, const int* in_sizes, int n_in,
                              void* d_out, int out_size, void* d_ws, size_t ws_size,
                              hipStream_t stream) {
    const float* rois      = (const float*)d_in[0];
    const float* cls_prob  = (const float*)d_in[1];
    const float* mask_prob = (const float*)d_in[2];
    const int*   cls_idx   = (const int*)d_in[3];
    int* ws = (int*)d_ws;
    float* out = (float*)d_out;

    k_rank<<<dim3(1), dim3(128), 0, stream>>>(cls_prob, rois, cls_idx, ws);
    k_mask<<<dim3(NINST), dim3(256), 0, stream>>>(mask_prob, ws);
    k_scan<<<dim3(1), dim3(256), 0, stream>>>(ws, out);
    // 625 blocks x 256 thr x 4 floats = exactly 640000 px per slot
    k_out<<<dim3(IMG * IMG / 1024, NINST), dim3(256), 0, stream>>>(mask_prob, ws, out);
}

// Round 2
// 355.723 us; speedup vs baseline: 1.0512x; 1.0512x over previous
//
#include <hip/hip_runtime.h>

#define NINST 100
#define MLOG 28
#define IMG 800
#define LOGSZ (MLOG * MLOG) /* 784 */

// ws layout (32-bit words):
//  [0..99]    order (original index of n-th highest cls_prob)
//  [100..199] cls (0-based class of ordered instance)
//  [200..599] box (x0,y0,x1,y1 per ordered instance, int-truncated)
//  [600..699] msum
//  [800..899] slot_n (ordered-instance index for output slot s)
//  [900]      nkeep
//  [1024..]   bit-packed masks, stride 3648 words (12 x 304 rows), word col
//             aligned to GLOBAL word grid (word = x/32) so AND needs no shift.
#define OFF_ORDER 0
#define OFF_CLS   100
#define OFF_BOX   200
#define OFF_MSUM  600
#define OFF_SLOT  800
#define OFF_NK    900
#define OFF_MASK  1024
#define ROWW      12
#define MSTRIDE   (ROWW * 304)
#define NZBLK     (IMG * IMG / 1024) /* 62500 zero-fill blocks, 1024 floats each */

// Fused: blocks [0,100) rank (redundantly, from LDS) + rasterize bit-masks;
// blocks [100, 100+NZBLK) stream zeros over the whole mask_energy output.
// The zero-fill has NO dependencies, so it overlaps the raster work instead
// of serializing after the scan like R0's k_out did.
__global__ __launch_bounds__(256) void k_mask_zero(const float* __restrict__ mask_prob,
                                                   const float* __restrict__ cls_prob,
                                                   const float* __restrict__ rois,
                                                   const int* __restrict__ cls_idx,
                                                   int* __restrict__ ws,
                                                   float* __restrict__ out) {
    int b = blockIdx.x, tid = threadIdx.x;
    if (b >= NINST) { // streaming zero path: 256 thr x float4 = 1024 floats/blk
        size_t pi = (size_t)(b - NINST) * 256 + tid;
        ((float4*)(out + NINST))[pi] = make_float4(0.f, 0.f, 0.f, 0.f);
        return;
    }
    __shared__ float s_p[NINST];
    __shared__ int s_order[NINST];
    __shared__ float lg[LOGSZ];
    __shared__ int red[256];
    if (tid < NINST) s_p[tid] = cls_prob[tid];
    __syncthreads();
    if (tid < NINST) {
        float p = s_p[tid];
        int r = 0;
        for (int j = 0; j < NINST; j++) {
            float q = s_p[j];
            r += (q > p) || (q == p && j < tid); // stable argsort(-cls_prob)
        }
        s_order[r] = tid;
    }
    __syncthreads();
    int n = b;
    int orig = s_order[n];
    int x0 = (int)rois[4 * orig], y0 = (int)rois[4 * orig + 1];
    int x1 = (int)rois[4 * orig + 2], y1 = (int)rois[4 * orig + 3];
    if (b == 0 && tid < NINST) { // publish metadata for k_scan / k_box
        int o = s_order[tid];
        ws[OFF_ORDER + tid] = o;
        ws[OFF_CLS + tid] = cls_idx[o] - 1;
#pragma unroll
        for (int k = 0; k < 4; k++)
            ws[OFF_BOX + 4 * tid + k] = (int)rois[4 * o + k];
    }
    for (int i = tid; i < LOGSZ; i += 256) lg[i] = mask_prob[orig * LOGSZ + i];
    __syncthreads();
    int xs = max(x0, 0), xe = min(x1 + 1, IMG);
    int ys = max(y0, 0), ye = min(y1 + 1, IMG);
    int wx0 = xs >> 5, nw = ((xe + 31) >> 5) - wx0, nrows = ye - ys;
    float wf = fmaxf((float)(x1 - x0 + 1), 1.f), hf = fmaxf((float)(y1 - y0 + 1), 1.f);
    float rx = 28.f / wf, ry = 28.f / hf;
    unsigned* mb = (unsigned*)(ws + OFF_MASK) + n * MSTRIDE;
    int total = nrows * nw, cnt = 0;
    for (int t = tid; t < total; t += 256) {
        int row = t / nw, wc = t - row * nw;
        int y = ys + row;
        float sy = ((float)y - (float)y0 + 0.5f) * ry - 0.5f;
        sy = fminf(fmaxf(sy, 0.f), 27.f);
        int iy0 = (int)sy, iy1 = min(iy0 + 1, 27);
        float fy = sy - (float)iy0;
        const float* r0 = lg + iy0 * MLOG;
        const float* r1 = lg + iy1 * MLOG;
        unsigned bits = 0u;
        int xbase = (wx0 + wc) << 5;
        int j0 = max(xs - xbase, 0), j1 = min(xe - xbase, 32);
        for (int j = j0; j < j1; j++) {
            int xx = xbase + j;
            float sx = ((float)xx - (float)x0 + 0.5f) * rx - 0.5f;
            sx = fminf(fmaxf(sx, 0.f), 27.f);
            int ix0 = (int)sx, ix1 = min(ix0 + 1, 27);
            float fx = sx - (float)ix0;
            float val = (1.f - fy) * ((1.f - fx) * r0[ix0] + fx * r0[ix1]) +
                        fy * ((1.f - fx) * r1[ix0] + fx * r1[ix1]);
            bits |= (val > 0.f) ? (1u << j) : 0u;
        }
        mb[row * ROWW + wc] = bits;
        cnt += __popc(bits);
    }
    red[tid] = cnt;
    __syncthreads();
    for (int s = 128; s; s >>= 1) {
        if (tid < s) red[tid] += red[tid + s];
        __syncthreads();
    }
    if (tid == 0) ws[OFF_MSUM + n] = red[0];
}

// Single block: sequential keep scan (union overlap on the fly, candidates
// restricted to earlier KEPT same-class box-overlapping instances).
__global__ __launch_bounds__(256) void k_scan(int* __restrict__ ws, float* __restrict__ out) {
    int tid = threadIdx.x;
    __shared__ int s_box[4 * NINST];
    __shared__ int s_cls[NINST];
    __shared__ int s_msum[NINST];
    __shared__ int s_keep[NINST];
    __shared__ int s_cand[32];
    __shared__ int s_ncand;
    __shared__ int red[256];
    for (int i = tid; i < NINST; i += 256) {
        s_cls[i] = ws[OFF_CLS + i];
        s_msum[i] = ws[OFF_MSUM + i];
    }
    for (int i = tid; i < 4 * NINST; i += 256) s_box[i] = ws[OFF_BOX + i];
    const unsigned* maskbase = (const unsigned*)(ws + OFF_MASK);
    __syncthreads();

    for (int n = 0; n < NINST; n++) {
        if (tid == 0) s_ncand = 0;
        __syncthreads(); // also publishes s_keep[n-1]
        if (tid < n && s_cls[tid] == s_cls[n] && s_keep[tid]) {
            int axs = max(s_box[4 * tid], 0), axe = min(s_box[4 * tid + 2] + 1, IMG);
            int ays = max(s_box[4 * tid + 1], 0), aye = min(s_box[4 * tid + 3] + 1, IMG);
            int nxs = max(s_box[4 * n], 0), nxe = min(s_box[4 * n + 2] + 1, IMG);
            int nys = max(s_box[4 * n + 1], 0), nye = min(s_box[4 * n + 3] + 1, IMG);
            if (axs < nxe && nxs < axe && ays < nye && nys < aye) {
                int k = atomicAdd(&s_ncand, 1);
                if (k < 32) s_cand[k] = tid;
            }
        }
        __syncthreads();
        int nc = min(s_ncand, 32);
        if (nc == 0) { // no same-class kept overlap -> ovl==0
            if (tid == 0) s_keep[n] = (s_msum[n] > 0);
            continue;
        }
        int nxs = max(s_box[4 * n], 0), nxe = min(s_box[4 * n + 2] + 1, IMG);
        int nys = max(s_box[4 * n + 1], 0), nye = min(s_box[4 * n + 3] + 1, IMG);
        int wx0 = nxs >> 5, nw = ((nxe + 31) >> 5) - wx0, nrows = nye - nys;
        const unsigned* mn = maskbase + n * MSTRIDE;
        int total = nrows * nw, ovl = 0;
        for (int t = tid; t < total; t += 256) {
            int row = t / nw, wc = t - row * nw;
            unsigned bits = mn[row * ROWW + wc];
            if (!bits) continue;
            int y = nys + row, wa = wx0 + wc;
            unsigned img = 0;
            for (int k = 0; k < nc; k++) {
                int m = s_cand[k];
                int mys = max(s_box[4 * m + 1], 0), mye = min(s_box[4 * m + 3] + 1, IMG);
                int mxs = max(s_box[4 * m], 0), mxe = min(s_box[4 * m + 2] + 1, IMG);
                int mwx0 = mxs >> 5, mnw = ((mxe + 31) >> 5) - mwx0;
                int rr = y - mys, cc = wa - mwx0;
                if (rr >= 0 && rr < (mye - mys) && cc >= 0 && cc < mnw)
                    img |= maskbase[m * MSTRIDE + rr * ROWW + cc];
            }
            ovl += __popc(bits & img);
        }
        red[tid] = ovl;
        __syncthreads();
        for (int s = 128; s; s >>= 1) {
            if (tid < s) red[tid] += red[tid + s];
            __syncthreads();
        }
        if (tid == 0) {
            int msum = s_msum[n];
            s_keep[n] = (msum > 0) && ((float)red[0] <= 0.3f * (float)msum);
        }
    }
    __syncthreads();
    if (tid == 0) {
        int nk = 0;
        for (int n = 0; n < NINST; n++) {
            if (s_keep[n]) {
                ws[OFF_SLOT + nk] = n;
                out[nk] = (float)ws[OFF_ORDER + n];
                nk++;
            }
        }
        ws[OFF_NK] = nk;
        for (int s = nk; s < NINST; s++) out[s] = -1.f;
    }
}

// Writes kept boxes' interiors only (output already zeroed by k_mask_zero).
// Aligned float4 spans: x in [xs&~3, align4(xe)); out-of-box lanes write 0
// (rewriting an already-zero value is harmless). Row starts are 4-aligned
// (100, 640000, 800 all divisible by 4).
__global__ __launch_bounds__(256) void k_box(const float* __restrict__ mask_prob,
                                             const int* __restrict__ ws,
                                             float* __restrict__ out) {
    int slot = blockIdx.y, tid = threadIdx.x;
    if (slot >= ws[OFF_NK]) return; // uniform per block
    int n = ws[OFF_SLOT + slot];
    const int* box = ws + OFF_BOX + 4 * n;
    int x0 = box[0], y0 = box[1], x1 = box[2], y1 = box[3];
    int xs = max(x0, 0), xe = min(x1 + 1, IMG);
    int ys = max(y0, 0), ye = min(y1 + 1, IMG);
    int xa = xs & ~3;
    int w4 = (xe - xa + 3) >> 2;
    int rows = ye - ys;
    int total = rows * w4;
    __shared__ float lg[LOGSZ];
    int orig = ws[OFF_ORDER + n];
    for (int i = tid; i < LOGSZ; i += 256) lg[i] = mask_prob[orig * LOGSZ + i];
    __syncthreads();
    float wf = fmaxf((float)(x1 - x0 + 1), 1.f), hf = fmaxf((float)(y1 - y0 + 1), 1.f);
    float rx = 28.f / wf, ry = 28.f / hf;
    float* base = out + NINST + (size_t)slot * (IMG * IMG);
    for (int t = blockIdx.x * 256 + tid; t < total; t += gridDim.x * 256) {
        int row = t / w4, c4 = t - row * w4;
        int y = ys + row, xb = xa + (c4 << 2);
        float sy = ((float)y - (float)y0 + 0.5f) * ry - 0.5f;
        sy = fminf(fmaxf(sy, 0.f), 27.f);
        int iy0 = (int)sy, iy1 = min(iy0 + 1, 27);
        float fy = sy - (float)iy0;
        const float* r0 = lg + iy0 * MLOG;
        const float* r1 = lg + iy1 * MLOG;
        float v[4];
#pragma unroll
        for (int j = 0; j < 4; j++) {
            int xx = xb + j;
            float val = 0.f;
            if (xx >= xs && xx < xe) {
                float sx = ((float)xx - (float)x0 + 0.5f) * rx - 0.5f;
                sx = fminf(fmaxf(sx, 0.f), 27.f);
                int ix0 = (int)sx, ix1 = min(ix0 + 1, 27);
                float fx = sx - (float)ix0;
                val = (1.f - fy) * ((1.f - fx) * r0[ix0] + fx * r0[ix1]) +
                      fy * ((1.f - fx) * r1[ix0] + fx * r1[ix1]);
            }
            v[j] = val;
        }
        *(float4*)(base + (size_t)y * IMG + xb) = make_float4(v[0], v[1], v[2], v[3]);
    }
}

extern "C" void kernel_launch(void* const* d_in, const int* in_sizes, int n_in,
                              void* d_out, int out_size, void* d_ws, size_t ws_size,
                              hipStream_t stream) {
    const float* rois      = (const float*)d_in[0];
    const float* cls_prob  = (const float*)d_in[1];
    const float* mask_prob = (const float*)d_in[2];
    const int*   cls_idx   = (const int*)d_in[3];
    int* ws = (int*)d_ws;
    float* out = (float*)d_out;

    k_mask_zero<<<dim3(NINST + NZBLK), dim3(256), 0, stream>>>(mask_prob, cls_prob, rois, cls_idx, ws, out);
    k_scan<<<dim3(1), dim3(256), 0, stream>>>(ws, out);
    // max box 301x301 -> rows*w4 <= 301*77 = 23177 <= 91*256
    k_box<<<dim3(91, NINST), dim3(256), 0, stream>>>(mask_prob, ws, out);
}

// Round 3
// 345.231 us; speedup vs baseline: 1.0831x; 1.0304x over previous
//
#include <hip/hip_runtime.h>

#define NINST 100
#define MLOG 28
#define IMG 800
#define LOGSZ (MLOG * MLOG) /* 784 */

// ws layout (32-bit words):
//  [0..99]    order (original index of n-th highest cls_prob)
//  [100..199] cls (0-based class of ordered instance)
//  [200..599] box (x0,y0,x1,y1 per ordered instance, int-truncated)
//  [600..699] msum
//  [800..899] slot_n (ordered-instance index for output slot s)
//  [900]      nkeep
//  [901]      npairs
//  [1024..]   bit-packed masks, stride 3648 words (12 x 304 rows), word col
//             aligned to GLOBAL word grid (word = x/32) so AND needs no shift.
//  [365824..] pair list (i, j, ovl) triplets, capacity 512
#define OFF_ORDER 0
#define OFF_CLS   100
#define OFF_BOX   200
#define OFF_MSUM  600
#define OFF_SLOT  800
#define OFF_NK    900
#define OFF_NPAIR 901
#define OFF_MASK  1024
#define ROWW      12
#define MSTRIDE   (ROWW * 304)
#define OFF_PAIRS (OFF_MASK + NINST * MSTRIDE) /* 365824 */
#define PAIR_CAP  512
#define NZBLK     (IMG * IMG / 1024) /* 62500 zero-fill blocks, 1024 floats each */

// Fused: blocks [0,100) rank (redundantly, from LDS) + rasterize bit-masks;
// blocks [100, 100+NZBLK) stream zeros over the whole mask_energy output
// (zero-fill has no deps -> overlaps raster instead of serializing later).
__global__ __launch_bounds__(256) void k_mask_zero(const float* __restrict__ mask_prob,
                                                   const float* __restrict__ cls_prob,
                                                   const float* __restrict__ rois,
                                                   const int* __restrict__ cls_idx,
                                                   int* __restrict__ ws,
                                                   float* __restrict__ out) {
    int b = blockIdx.x, tid = threadIdx.x;
    if (b >= NINST) { // streaming zero path: 256 thr x float4 = 1024 floats/blk
        size_t pi = (size_t)(b - NINST) * 256 + tid;
        ((float4*)(out + NINST))[pi] = make_float4(0.f, 0.f, 0.f, 0.f);
        return;
    }
    __shared__ float s_p[NINST];
    __shared__ int s_order[NINST];
    __shared__ float lg[LOGSZ];
    __shared__ int red[256];
    if (tid < NINST) s_p[tid] = cls_prob[tid];
    __syncthreads();
    if (tid < NINST) {
        float p = s_p[tid];
        int r = 0;
        for (int j = 0; j < NINST; j++) {
            float q = s_p[j];
            r += (q > p) || (q == p && j < tid); // stable argsort(-cls_prob)
        }
        s_order[r] = tid;
    }
    __syncthreads();
    int n = b;
    int orig = s_order[n];
    int x0 = (int)rois[4 * orig], y0 = (int)rois[4 * orig + 1];
    int x1 = (int)rois[4 * orig + 2], y1 = (int)rois[4 * orig + 3];
    if (b == 0) { // publish metadata for downstream kernels
        if (tid == 0) ws[OFF_NPAIR] = 0;
        if (tid < NINST) {
            int o = s_order[tid];
            ws[OFF_ORDER + tid] = o;
            ws[OFF_CLS + tid] = cls_idx[o] - 1;
#pragma unroll
            for (int k = 0; k < 4; k++)
                ws[OFF_BOX + 4 * tid + k] = (int)rois[4 * o + k];
        }
    }
    for (int i = tid; i < LOGSZ; i += 256) lg[i] = mask_prob[orig * LOGSZ + i];
    __syncthreads();
    int xs = max(x0, 0), xe = min(x1 + 1, IMG);
    int ys = max(y0, 0), ye = min(y1 + 1, IMG);
    int wx0 = xs >> 5, nw = ((xe + 31) >> 5) - wx0, nrows = ye - ys;
    float wf = fmaxf((float)(x1 - x0 + 1), 1.f), hf = fmaxf((float)(y1 - y0 + 1), 1.f);
    float rx = 28.f / wf, ry = 28.f / hf;
    unsigned* mb = (unsigned*)(ws + OFF_MASK) + n * MSTRIDE;
    int total = nrows * nw, cnt = 0;
    for (int t = tid; t < total; t += 256) {
        int row = t / nw, wc = t - row * nw;
        int y = ys + row;
        float sy = ((float)y - (float)y0 + 0.5f) * ry - 0.5f;
        sy = fminf(fmaxf(sy, 0.f), 27.f);
        int iy0 = (int)sy, iy1 = min(iy0 + 1, 27);
        float fy = sy - (float)iy0;
        const float* r0 = lg + iy0 * MLOG;
        const float* r1 = lg + iy1 * MLOG;
        unsigned bits = 0u;
        int xbase = (wx0 + wc) << 5;
        int j0 = max(xs - xbase, 0), j1 = min(xe - xbase, 32);
        for (int j = j0; j < j1; j++) {
            int xx = xbase + j;
            float sx = ((float)xx - (float)x0 + 0.5f) * rx - 0.5f;
            sx = fminf(fmaxf(sx, 0.f), 27.f);
            int ix0 = (int)sx, ix1 = min(ix0 + 1, 27);
            float fx = sx - (float)ix0;
            float val = (1.f - fy) * ((1.f - fx) * r0[ix0] + fx * r0[ix1]) +
                        fy * ((1.f - fx) * r1[ix0] + fx * r1[ix1]);
            bits |= (val > 0.f) ? (1u << j) : 0u;
        }
        mb[row * ROWW + wc] = bits;
        cnt += __popc(bits);
    }
    red[tid] = cnt;
    __syncthreads();
    for (int s = 128; s; s >>= 1) {
        if (tid < s) red[tid] += red[tid + s];
        __syncthreads();
    }
    if (tid == 0) ws[OFF_MSUM + n] = red[0];
}

// One wave per (i,j) pair, i<j: if same class, both non-empty, boxes overlap,
// compute popcount(mask_i & mask_j) and append to compact pair list.
__global__ __launch_bounds__(64) void k_pairs(int* __restrict__ ws) {
    int i = blockIdx.x, j = blockIdx.y, tid = threadIdx.x;
    if (i >= j) return;
    if (ws[OFF_CLS + i] != ws[OFF_CLS + j]) return;
    if (ws[OFF_MSUM + i] == 0 || ws[OFF_MSUM + j] == 0) return;
    const int* bi = ws + OFF_BOX + 4 * i;
    const int* bj = ws + OFF_BOX + 4 * j;
    int ixs = max(bi[0], 0), ixe = min(bi[2] + 1, IMG);
    int iys = max(bi[1], 0), iye = min(bi[3] + 1, IMG);
    int jxs = max(bj[0], 0), jxe = min(bj[2] + 1, IMG);
    int jys = max(bj[1], 0), jye = min(bj[3] + 1, IMG);
    if (!(ixs < jxe && jxs < ixe && iys < jye && jys < iye)) return;
    int iwx0 = ixs >> 5, jwx0 = jxs >> 5;
    int wlo = max(iwx0, jwx0);
    int whi = min((ixe + 31) >> 5, (jxe + 31) >> 5);
    int rlo = max(iys, jys), rhi = min(iye, jye);
    int nw = whi - wlo, nrows = rhi - rlo;
    const unsigned* mi = (const unsigned*)(ws + OFF_MASK) + i * MSTRIDE;
    const unsigned* mj = (const unsigned*)(ws + OFF_MASK) + j * MSTRIDE;
    int total = nrows * nw, cnt = 0;
    for (int t = tid; t < total; t += 64) {
        int row = t / nw, wc = t - row * nw;
        int y = rlo + row, w = wlo + wc;
        unsigned a = mi[(y - iys) * ROWW + (w - iwx0)];
        unsigned b = mj[(y - jys) * ROWW + (w - jwx0)];
        cnt += __popc(a & b);
    }
    for (int off = 32; off; off >>= 1) cnt += __shfl_down(cnt, off);
    if (tid == 0) {
        int k = atomicAdd(ws + OFF_NPAIR, 1);
        if (k < PAIR_CAP) {
            ws[OFF_PAIRS + 3 * k] = i;
            ws[OFF_PAIRS + 3 * k + 1] = j;
            ws[OFF_PAIRS + 3 * k + 2] = cnt;
        }
    }
}

// Single block sequential keep scan — now pure LDS arithmetic via pair-ovl
// bounds: max_pair <= |union| <= sum_pair (int->float is monotone, so the
// reference's float compare is decided exactly when bounds agree). Rare
// ambiguous case falls back to block-parallel union popcount.
__global__ __launch_bounds__(256) void k_scan(int* __restrict__ ws, float* __restrict__ out) {
    int tid = threadIdx.x;
    __shared__ int s_box[4 * NINST];
    __shared__ int s_cls[NINST];
    __shared__ int s_msum[NINST];
    __shared__ int s_keep[NINST];
    __shared__ int s_cand[32];
    __shared__ int s_ncand, s_sum, s_max, s_need;
    __shared__ int s_pi[PAIR_CAP], s_pj[PAIR_CAP], s_po[PAIR_CAP];
    __shared__ int red[256];
    for (int i = tid; i < NINST; i += 256) {
        s_cls[i] = ws[OFF_CLS + i];
        s_msum[i] = ws[OFF_MSUM + i];
    }
    for (int i = tid; i < 4 * NINST; i += 256) s_box[i] = ws[OFF_BOX + i];
    int npair = min(ws[OFF_NPAIR], PAIR_CAP);
    for (int i = tid; i < npair; i += 256) {
        s_pi[i] = ws[OFF_PAIRS + 3 * i];
        s_pj[i] = ws[OFF_PAIRS + 3 * i + 1];
        s_po[i] = ws[OFF_PAIRS + 3 * i + 2];
    }
    const unsigned* maskbase = (const unsigned*)(ws + OFF_MASK);
    __syncthreads();

    for (int n = 0; n < NINST; n++) {
        if (tid == 0) { s_ncand = 0; s_sum = 0; s_max = 0; }
        __syncthreads(); // also publishes s_keep[n-1]
        if (tid < n && s_cls[tid] == s_cls[n] && s_keep[tid]) {
            int axs = max(s_box[4 * tid], 0), axe = min(s_box[4 * tid + 2] + 1, IMG);
            int ays = max(s_box[4 * tid + 1], 0), aye = min(s_box[4 * tid + 3] + 1, IMG);
            int nxs = max(s_box[4 * n], 0), nxe = min(s_box[4 * n + 2] + 1, IMG);
            int nys = max(s_box[4 * n + 1], 0), nye = min(s_box[4 * n + 3] + 1, IMG);
            if (axs < nxe && nxs < axe && ays < nye && nys < aye) {
                int k = atomicAdd(&s_ncand, 1);
                if (k < 32) s_cand[k] = tid;
                int ovl = 0;
                for (int q = 0; q < npair; q++)
                    if (s_pi[q] == tid && s_pj[q] == n) ovl = s_po[q];
                atomicAdd(&s_sum, ovl);
                atomicMax(&s_max, ovl);
            }
        }
        __syncthreads();
        if (tid == 0) {
            int msum = s_msum[n];
            float t = 0.3f * (float)msum;
            int keep, need = 0;
            if (s_ncand == 0 || (float)s_sum <= t) keep = (msum > 0);
            else if ((float)s_max > t) keep = 0;
            else { keep = 0; need = 1; } // max <= t < sum: exact union needed
            s_keep[n] = keep;
            s_need = need;
        }
        __syncthreads();
        if (s_need) { // rare: >=2 kept same-class overlapping predecessors, bounds disagree
            int nc = min(s_ncand, 32);
            int nxs = max(s_box[4 * n], 0), nxe = min(s_box[4 * n + 2] + 1, IMG);
            int nys = max(s_box[4 * n + 1], 0), nye = min(s_box[4 * n + 3] + 1, IMG);
            int wx0 = nxs >> 5, nw = ((nxe + 31) >> 5) - wx0, nrows = nye - nys;
            const unsigned* mn = maskbase + n * MSTRIDE;
            int total = nrows * nw, ovl = 0;
            for (int t2 = tid; t2 < total; t2 += 256) {
                int row = t2 / nw, wc = t2 - row * nw;
                unsigned bits = mn[row * ROWW + wc];
                if (!bits) continue;
                int y = nys + row, wa = wx0 + wc;
                unsigned img = 0;
                for (int k = 0; k < nc; k++) {
                    int m = s_cand[k];
                    int mys = max(s_box[4 * m + 1], 0), mye = min(s_box[4 * m + 3] + 1, IMG);
                    int mxs = max(s_box[4 * m], 0), mxe = min(s_box[4 * m + 2] + 1, IMG);
                    int mwx0 = mxs >> 5, mnw = ((mxe + 31) >> 5) - mwx0;
                    int rr = y - mys, cc = wa - mwx0;
                    if (rr >= 0 && rr < (mye - mys) && cc >= 0 && cc < mnw)
                        img |= maskbase[m * MSTRIDE + rr * ROWW + cc];
                }
                ovl += __popc(bits & img);
            }
            red[tid] = ovl;
            __syncthreads();
            for (int s = 128; s; s >>= 1) {
                if (tid < s) red[tid] += red[tid + s];
                __syncthreads();
            }
            if (tid == 0) {
                int msum = s_msum[n];
                s_keep[n] = (msum > 0) && ((float)red[0] <= 0.3f * (float)msum);
            }
        }
    }
    __syncthreads();
    if (tid == 0) {
        int nk = 0;
        for (int n = 0; n < NINST; n++) {
            if (s_keep[n]) {
                ws[OFF_SLOT + nk] = n;
                out[nk] = (float)ws[OFF_ORDER + n];
                nk++;
            }
        }
        ws[OFF_NK] = nk;
        for (int s = nk; s < NINST; s++) out[s] = -1.f;
    }
}

// Writes kept boxes' interiors only (output already zeroed by k_mask_zero).
__global__ __launch_bounds__(256) void k_box(const float* __restrict__ mask_prob,
                                             const int* __restrict__ ws,
                                             float* __restrict__ out) {
    int slot = blockIdx.y, tid = threadIdx.x;
    if (slot >= ws[OFF_NK]) return; // uniform per block
    int n = ws[OFF_SLOT + slot];
    const int* box = ws + OFF_BOX + 4 * n;
    int x0 = box[0], y0 = box[1], x1 = box[2], y1 = box[3];
    int xs = max(x0, 0), xe = min(x1 + 1, IMG);
    int ys = max(y0, 0), ye = min(y1 + 1, IMG);
    int xa = xs & ~3;
    int w4 = (xe - xa + 3) >> 2;
    int rows = ye - ys;
    int total = rows * w4;
    __shared__ float lg[LOGSZ];
    int orig = ws[OFF_ORDER + n];
    for (int i = tid; i < LOGSZ; i += 256) lg[i] = mask_prob[orig * LOGSZ + i];
    __syncthreads();
    float wf = fmaxf((float)(x1 - x0 + 1), 1.f), hf = fmaxf((float)(y1 - y0 + 1), 1.f);
    float rx = 28.f / wf, ry = 28.f / hf;
    float* base = out + NINST + (size_t)slot * (IMG * IMG);
    for (int t = blockIdx.x * 256 + tid; t < total; t += gridDim.x * 256) {
        int row = t / w4, c4 = t - row * w4;
        int y = ys + row, xb = xa + (c4 << 2);
        float sy = ((float)y - (float)y0 + 0.5f) * ry - 0.5f;
        sy = fminf(fmaxf(sy, 0.f), 27.f);
        int iy0 = (int)sy, iy1 = min(iy0 + 1, 27);
        float fy = sy - (float)iy0;
        const float* r0 = lg + iy0 * MLOG;
        const float* r1 = lg + iy1 * MLOG;
        float v[4];
#pragma unroll
        for (int j = 0; j < 4; j++) {
            int xx = xb + j;
            float val = 0.f;
            if (xx >= xs && xx < xe) {
                float sx = ((float)xx - (float)x0 + 0.5f) * rx - 0.5f;
                sx = fminf(fmaxf(sx, 0.f), 27.f);
                int ix0 = (int)sx, ix1 = min(ix0 + 1, 27);
                float fx = sx - (float)ix0;
                val = (1.f - fy) * ((1.f - fx) * r0[ix0] + fx * r0[ix1]) +
                      fy * ((1.f - fx) * r1[ix0] + fx * r1[ix1]);
            }
            v[j] = val;
        }
        *(float4*)(base + (size_t)y * IMG + xb) = make_float4(v[0], v[1], v[2], v[3]);
    }
}

extern "C" void kernel_launch(void* const* d_in, const int* in_sizes, int n_in,
                              void* d_out, int out_size, void* d_ws, size_t ws_size,
                              hipStream_t stream) {
    const float* rois      = (const float*)d_in[0];
    const float* cls_prob  = (const float*)d_in[1];
    const float* mask_prob = (const float*)d_in[2];
    const int*   cls_idx   = (const int*)d_in[3];
    int* ws = (int*)d_ws;
    float* out = (float*)d_out;

    k_mask_zero<<<dim3(NINST + NZBLK), dim3(256), 0, stream>>>(mask_prob, cls_prob, rois, cls_idx, ws, out);
    k_pairs<<<dim3(NINST, NINST), dim3(64), 0, stream>>>(ws);
    k_scan<<<dim3(1), dim3(256), 0, stream>>>(ws, out);
    // max box 301x301 -> rows*w4 <= 301*77 = 23177 <= 91*256
    k_box<<<dim3(91, NINST), dim3(256), 0, stream>>>(mask_prob, ws, out);
}